// Round 4
// baseline (250.763 us; speedup 1.0000x reference)
//
#include <hip/hip_runtime.h>

// GraphAttentionLayer, B=8, N=1024, F_IN=64, HEADS=8, D=64.
// exp(leaky_relu(s_i + t_j)) factorizes across the LeakyReLU branch, so the
// softmax reduces to prefix sums over sorted s / sorted t.  O(N log N + N D).
//
// R6: SINGLE persistent kernel (grid 256 x 1024, 1 block/CU co-resident) with
// device-scope spin barriers.  Evidence: per-launch boundary ~10-15us (R3/R5
// deltas) while total GPU work is ~30us -> boundaries dominate.  Unlike R5,
// the INC phase runs at FULL chip width (2048 chunk-waves over 256 blocks).
// Phases: A Wh+s/t | B 64 sorts | B2 INC chunk prefixes | B3 offset scan | C out.

#define B_  8
#define N_  1024
#define H_  8
#define D_  64
#define BH_ 64
#define CH_ 32          // chunks per (b,h)
#define CL_ 32          // ranks per chunk

__device__ __forceinline__ float bcast_lane(float v, int l) {
  return __int_as_float(__builtin_amdgcn_readlane(__float_as_int(v), l));
}

__device__ __forceinline__ void gridbar(unsigned int* cnt, unsigned int target) {
  __syncthreads();
  if (threadIdx.x == 0) {
    __threadfence();   // prior global writes agent-visible
    __hip_atomic_fetch_add(cnt, 1u, __ATOMIC_RELEASE, __HIP_MEMORY_SCOPE_AGENT);
    while (__hip_atomic_load(cnt, __ATOMIC_ACQUIRE, __HIP_MEMORY_SCOPE_AGENT) < target)
      __builtin_amdgcn_s_sleep(1);
    __threadfence();
  }
  __syncthreads();
}

__global__ __launch_bounds__(1024) void k_fused(
    const float* __restrict__ h, const float* __restrict__ W,
    const float* __restrict__ a,
    const float* __restrict__ outW, const float* __restrict__ outb,
    float* __restrict__ out,
    float* __restrict__ Wh, float* __restrict__ sArr, float* __restrict__ tArr,
    int* __restrict__ tsi, float* __restrict__ uArr, float* __restrict__ vArr,
    int* __restrict__ qrk,
    float* __restrict__ INC1, float* __restrict__ INC2,
    float2* __restrict__ csG, float2* __restrict__ cOff,
    unsigned int* __restrict__ bar) {
  __shared__ float sL[1024];
  __shared__ float tvL[1024];
  __shared__ int   tiL[1024];
  __shared__ float cum1L[1024], cum001L[1024];
  __shared__ float ws1[16], ws2[16];
  __shared__ float part[2 * 8 * 8 * 64];          // 32KB, phase C
  __shared__ int   rkI[32 * 8];
  __shared__ float esL[32 * 8], es001L[32 * 8];

  const int tid = threadIdx.x;
  const int lane = tid & 63;
  const int wv = tid >> 6;
  const int bi = blockIdx.x;

  // ---------------- Phase A: Wh = h@W, s/t via butterfly ----------------
  {
    const int g = wv >> 2, w2 = wv & 3;          // g: row subgroup, w2: head pair
    const int row0 = bi * 32 + g * 8;
    const int b = row0 >> 10;
    float hreg[8];
#pragma unroll
    for (int r = 0; r < 8; ++r) hreg[r] = h[(row0 + r) * 64 + lane];
    const float a_s = a[lane];
    const float a_t = a[64 + lane];

    float acc0[8], acc1[8];
#pragma unroll
    for (int r = 0; r < 8; ++r) { acc0[r] = 0.f; acc1[r] = 0.f; }
#pragma unroll 4
    for (int k = 0; k < 64; ++k) {
      const float w0 = W[k * 512 + w2 * 64 + lane];
      const float w1 = W[k * 512 + 256 + w2 * 64 + lane];
#pragma unroll
      for (int r = 0; r < 8; ++r) {
        const float hv = bcast_lane(hreg[r], k);
        acc0[r] += hv * w0;
        acc1[r] += hv * w1;
      }
    }
    const int hh0 = w2, hh1 = w2 + 4;
#pragma unroll
    for (int r = 0; r < 8; ++r) {
      const int n = (row0 + r) & (N_ - 1);
      Wh[((b * H_ + hh0) * N_ + n) * D_ + lane] = acc0[r];
      Wh[((b * H_ + hh1) * N_ + n) * D_ + lane] = acc1[r];
    }
#pragma unroll
    for (int r = 0; r < 8; ++r) {
      const int n = (row0 + r) & (N_ - 1);
      float s0 = acc0[r] * a_s, t0 = acc0[r] * a_t;
      float s1 = acc1[r] * a_s, t1 = acc1[r] * a_t;
#pragma unroll
      for (int m = 32; m > 0; m >>= 1) {
        s0 += __shfl_xor(s0, m); t0 += __shfl_xor(t0, m);
        s1 += __shfl_xor(s1, m); t1 += __shfl_xor(t1, m);
      }
      if (lane == 0) {
        sArr[(b * H_ + hh0) * N_ + n] = s0;
        tArr[(b * H_ + hh0) * N_ + n] = t0;
        sArr[(b * H_ + hh1) * N_ + n] = s1;
        tArr[(b * H_ + hh1) * N_ + n] = t1;
      }
    }
  }
  gridbar(bar, 256);

  // ---------------- Phase B: sort + scans + u/v/qrk (blocks 0..63) -------
  if (bi < BH_) {
    const int bh = bi;
    const float orig_s = sArr[bh * N_ + tid];
    float sv_r = orig_s;
    float tv_r = tArr[bh * N_ + tid];
    int   ti_r = tid;

    for (int size = 2; size <= 1024; size <<= 1) {
      for (int stride = size >> 1; stride > 0; stride >>= 1) {
        const bool up = ((tid & size) == 0);
        const bool lower = ((tid & stride) == 0);
        float psv, ptv; int pti;
        if (stride >= 64) {
          sL[tid] = sv_r; tvL[tid] = tv_r; tiL[tid] = ti_r;
          __syncthreads();
          const int p = tid ^ stride;
          psv = sL[p]; ptv = tvL[p]; pti = tiL[p];
          __syncthreads();
        } else {
          psv = __shfl_xor(sv_r, stride);
          ptv = __shfl_xor(tv_r, stride);
          pti = __shfl_xor(ti_r, stride);
        }
        const bool sameDir = (up == lower);
        const bool pLessS = (psv < sv_r);
        if (pLessS == sameDir) sv_r = psv;
        const bool pLessT = (ptv < tv_r) || (ptv == tv_r && pti < ti_r);
        if (pLessT == sameDir) { tv_r = ptv; ti_r = pti; }
      }
    }
    sL[tid] = sv_r; tvL[tid] = tv_r;

    // inclusive scans of exp(s), exp(0.01 s)
    float c1 = __expf(sv_r), c001 = __expf(0.01f * sv_r);
    {
      float a1 = c1, a2 = c001;
#pragma unroll
      for (int off = 1; off < 64; off <<= 1) {
        const float x1 = __shfl_up(a1, off);
        const float x2 = __shfl_up(a2, off);
        if (lane >= off) { a1 += x1; a2 += x2; }
      }
      if (lane == 63) { ws1[wv] = a1; ws2[wv] = a2; }
      __syncthreads();
      float o1 = 0.f, o2 = 0.f;
      for (int ww = 0; ww < 16; ++ww) {
        if (ww < wv) { o1 += ws1[ww]; o2 += ws2[ww]; }
      }
      c1 = a1 + o1; c001 = a2 + o2;
    }
    cum1L[tid] = c1; cum001L[tid] = c001;
    __syncthreads();
    const float totalHi = cum1L[1023];

    // Z, u, v per sorted-t rank
    {
      const float tj = tv_r;
      const float th = -tj;
      int lo = 0, hi = 1024;
      while (lo < hi) { const int mid = (lo + hi) >> 1; if (sL[mid] <= th) lo = mid + 1; else hi = mid; }
      const float S_lo = (lo > 0) ? cum001L[lo - 1] : 0.f;
      const float S_hi = totalHi - ((lo > 0) ? cum1L[lo - 1] : 0.f);
      const float et = __expf(tj), et001 = __expf(0.01f * tj);
      const float Z = et * S_hi + et001 * S_lo;
      uArr[bh * N_ + tid] = et / Z;
      vArr[bh * N_ + tid] = et001 / Z;
      tsi[bh * N_ + tid] = ti_r;
    }
    // query rank for row i
    {
      const float th = -orig_s;
      int lo = 0, hi = 1024;
      while (lo < hi) { const int mid = (lo + hi) >> 1; if (tvL[mid] <= th) lo = mid + 1; else hi = mid; }
      qrk[bh * N_ + tid] = lo;
    }
  }
  gridbar(bar, 512);

  // ------ Phase B2: chunk-local INC prefixes + chunk sums (full chip) ----
  if (wv < 8) {
    const int id = bi * 8 + wv;                 // 0..2047
    const int bh = id >> 5, c = id & (CH_ - 1);
    const int rb = bh * N_ + c * CL_;
    int jv = 0; float uv = 0.f, vvx = 0.f;
    if (lane < 32) {
      jv  = tsi[rb + lane];
      uv  = uArr[rb + lane];
      vvx = vArr[rb + lane];
    }
    const int whb = bh * (N_ * D_);
    float r1 = 0.f, r2 = 0.f;
#pragma unroll 8
    for (int k2 = 0; k2 < CL_; ++k2) {
      const int   j  = __builtin_amdgcn_readlane(jv, k2);
      const float uu = bcast_lane(uv, k2);
      const float vv2 = bcast_lane(vvx, k2);
      const float w = Wh[whb + j * 64 + lane];
      r1 += uu * w; r2 += vv2 * w;
      INC1[(rb + k2) * 64 + lane] = r1;
      INC2[(rb + k2) * 64 + lane] = r2;
    }
    csG[(bh * CH_ + c) * 64 + lane] = make_float2(r1, r2);
  }
  gridbar(bar, 768);

  // ------ Phase B3: exclusive chunk-offset scan per bh (blocks 0..63) ----
  if (bi < BH_ && wv == 0) {
    const int cb = bi * 33;
    float o1 = 0.f, o2 = 0.f;
    for (int m = 0; m < CH_; ++m) {
      const float2 cv = csG[(bi * CH_ + m) * 64 + lane];
      cOff[(cb + m) * 64 + lane] = make_float2(o1, o2);
      o1 += cv.x; o2 += cv.y;
    }
    cOff[(cb + 32) * 64 + lane] = make_float2(o1, o2);
  }
  gridbar(bar, 1024);

  // ---------------- Phase C: hp + output GEMM (32 rows/block) ------------
  {
    const int hb = wv >> 3, p = wv & 7;         // half-block, head
    const int row0 = bi * 32;
    const int b = row0 >> 10;
    if (tid < 256) {
      const int r = tid >> 3, hh = tid & 7;
      const int bh = b * H_ + hh;
      const int n = (row0 + r) & (N_ - 1);
      const float si = sArr[bh * N_ + n];
      rkI[tid] = qrk[bh * N_ + n];
      esL[tid] = __expf(si);
      es001L[tid] = __expf(0.01f * si);
    }
    __syncthreads();

    const int bh = b * H_ + p;
    const int cb = bh * 33;
    const float T1 = cOff[(cb + 32) * 64 + lane].x;
    float hpv[16];
#pragma unroll
    for (int r = 0; r < 16; ++r) {
      const int rr = hb * 16 + r;
      const int rk = rkI[rr * 8 + p];
      float i1 = 0.f, i2 = 0.f;
      if (rk > 0) {
        const int idx = rk - 1, cc = idx >> 5;
        const float2 co = cOff[(cb + cc) * 64 + lane];
        i1 = INC1[(bh * N_ + idx) * 64 + lane] + co.x;
        i2 = INC2[(bh * N_ + idx) * 64 + lane] + co.y;
      }
      hpv[r] = esL[rr * 8 + p] * (T1 - i1) + es001L[rr * 8 + p] * i2;
    }

    float acc[16];
#pragma unroll
    for (int r = 0; r < 16; ++r) acc[r] = 0.f;
#pragma unroll 4
    for (int kc = 0; kc < 64; ++kc) {
      const float wvv = outW[(p * 64 + kc) * 64 + lane];
#pragma unroll
      for (int r = 0; r < 16; ++r) acc[r] += bcast_lane(hpv[r], kc) * wvv;
    }

    float* pp = part + hb * (8 * 8 * 64);
    for (int half = 0; half < 2; ++half) {
#pragma unroll
      for (int r = 0; r < 8; ++r) pp[(p * 8 + r) * 64 + lane] = acc[half * 8 + r];
      __syncthreads();
      {
        float ssum = 0.f;
#pragma unroll
        for (int p2 = 0; p2 < 8; ++p2) ssum += pp[(p2 * 8 + p) * 64 + lane];
        out[(row0 + hb * 16 + half * 8 + p) * 64 + lane] = outb[lane] + ssum;
      }
      __syncthreads();
    }
  }
}

extern "C" void kernel_launch(void* const* d_in, const int* in_sizes, int n_in,
                              void* d_out, int out_size, void* d_ws, size_t ws_size,
                              hipStream_t stream) {
  const float* h    = (const float*)d_in[0];
  // d_in[1] = adj: all-ones, unused by the module
  const float* W    = (const float*)d_in[2];
  const float* a    = (const float*)d_in[3];
  const float* outW = (const float*)d_in[4];
  const float* outb = (const float*)d_in[5];
  float* out = (float*)d_out;

  float* ws   = (float*)d_ws;
  float* Wh   = ws;                                   // BH*N*D
  float* sArr = Wh + (size_t)BH_ * N_ * D_;           // BH*N each
  float* tArr = sArr + BH_ * N_;
  float* uArr = tArr + BH_ * N_;
  float* vArr = uArr + BH_ * N_;
  float* INC1 = vArr + BH_ * N_;                      // BH*N*D
  float* INC2 = INC1 + (size_t)BH_ * N_ * D_;
  int*   tsi  = (int*)(INC2 + (size_t)BH_ * N_ * D_); // BH*N each
  int*   qrk  = tsi + BH_ * N_;
  float2* csG  = (float2*)(qrk + BH_ * N_);           // BH*CH*64
  float2* cOff = csG + (size_t)BH_ * CH_ * 64;        // BH*33*64
  unsigned int* bar = (unsigned int*)(cOff + (size_t)BH_ * 33 * 64);

  hipMemsetAsync(bar, 0, sizeof(unsigned int), stream);
  hipLaunchKernelGGL(k_fused, dim3(256), dim3(1024), 0, stream,
                     h, W, a, outW, outb, out,
                     Wh, sArr, tArr, tsi, uArr, vArr, qrk,
                     INC1, INC2, csG, cOff, bar);
}

// Round 5
// 204.533 us; speedup vs baseline: 1.2260x; 1.2260x over previous
//
#include <hip/hip_runtime.h>

// GraphAttentionLayer, B=8, N=1024, F_IN=64, HEADS=8, D=64.
// exp(leaky_relu(s_i + t_j)) factorizes across the LeakyReLU branch, so the
// softmax reduces to prefix sums over sorted s / sorted t.  O(N log N + N D).
//
// R7: 2 kernels (model from R2-R6: dur = F(62) + 10/launch + work).
//  K1 = R4's k_wh verbatim (full chip).
//  K2 = 256 blocks = (bh, quarter): each quarter REDUNDANTLY sorts its (b,h)
//    (wall-free: parallel CUs), chunk sums (chunk=16) from own sort registers
//    via readlane, in-LDS chunk scan, then for its 256 rows: tail-sum queries
//    (<=16 gathers) replace the INC1/INC2 arrays entirely (-33MB traffic,
//    -1 kernel), hp in registers, out-GEMM via readlane, atomicAdd into
//    zeroed out (bias from the h==0 blocks).  Kernel boundary K1->K2 keeps
//    the L2 flush that R6's fused version lost (cross-XCD dirty-line stalls).

#define B_  8
#define N_  1024
#define H_  8
#define D_  64
#define BH_ 64

__device__ __forceinline__ float bcast_lane(float v, int l) {
  return __int_as_float(__builtin_amdgcn_readlane(__float_as_int(v), l));
}

// ---------------- Kernel A: Wh = h@W (row-blocked), s/t = Wh . a ----------
__global__ __launch_bounds__(256) void k_wh(
    const float* __restrict__ h, const float* __restrict__ W,
    const float* __restrict__ a,
    float* __restrict__ Wh, float* __restrict__ sArr, float* __restrict__ tArr) {
  const int tid = threadIdx.x;
  const int lane = tid & 63;
  const int wid = tid >> 6;            // 0..3; acc0 -> head wid, acc1 -> head wid+4
  const int row0 = blockIdx.x * 16;
  const int b = row0 >> 10;

  float hreg[16];
#pragma unroll
  for (int r = 0; r < 16; ++r) hreg[r] = h[(row0 + r) * 64 + lane];
  const float a_s = a[lane];
  const float a_t = a[64 + lane];

  float acc0[16], acc1[16];
#pragma unroll
  for (int r = 0; r < 16; ++r) { acc0[r] = 0.f; acc1[r] = 0.f; }
#pragma unroll 4
  for (int k = 0; k < 64; ++k) {
    const float w0 = W[k * 512 + tid];
    const float w1 = W[k * 512 + tid + 256];
#pragma unroll
    for (int r = 0; r < 16; ++r) {
      const float hv = bcast_lane(hreg[r], k);   // SGPR broadcast, no LDS
      acc0[r] += hv * w0;
      acc1[r] += hv * w1;
    }
  }
  const int hh0 = wid, hh1 = wid + 4;
#pragma unroll
  for (int r = 0; r < 16; ++r) {
    const int n = (row0 + r) & (N_ - 1);
    Wh[((b * H_ + hh0) * N_ + n) * D_ + lane] = acc0[r];
    Wh[((b * H_ + hh1) * N_ + n) * D_ + lane] = acc1[r];
  }
#pragma unroll
  for (int r = 0; r < 16; ++r) {
    const int n = (row0 + r) & (N_ - 1);
    float s0 = acc0[r] * a_s, t0 = acc0[r] * a_t;
    float s1 = acc1[r] * a_s, t1 = acc1[r] * a_t;
#pragma unroll
    for (int m = 32; m > 0; m >>= 1) {
      s0 += __shfl_xor(s0, m); t0 += __shfl_xor(t0, m);
      s1 += __shfl_xor(s1, m); t1 += __shfl_xor(t1, m);
    }
    if (lane == 0) {
      sArr[(b * H_ + hh0) * N_ + n] = s0;
      tArr[(b * H_ + hh0) * N_ + n] = t0;
      sArr[(b * H_ + hh1) * N_ + n] = s1;
      tArr[(b * H_ + hh1) * N_ + n] = t1;
    }
  }
}

// ---- Kernel B: per (bh, quarter): redundant sort + scans + u/v/qrk,
//      chunk sums (16) + scan, tail-sum queries, hp, GEMM, atomic out ----
__global__ __launch_bounds__(1024) void k_rest(
    const float* __restrict__ sArr, const float* __restrict__ tArr,
    const float* __restrict__ Wh,
    const float* __restrict__ outW, const float* __restrict__ outb,
    float* __restrict__ out) {
  // union region: {sL,tvL,cum1L,cum001L} during sort/scan -> csOff after
  __shared__ float2 uni[65 * 64];                 // 33,280 B
  float* sL      = (float*)uni;                   // [1024]
  float* tvL     = sL + 1024;
  float* cum1L   = tvL + 1024;
  float* cum001L = cum1L + 1024;
  float2* csOff  = uni;                           // [65][64] after re-use
  __shared__ int   tiL[1024];
  __shared__ float uL[1024], vL[1024];
  __shared__ int   rkL[1024];
  __shared__ float esL[1024], es001L[1024];
  __shared__ float ws1[16], ws2[16];

  const int tid = threadIdx.x;
  const int lane = tid & 63;
  const int wv = tid >> 6;
  const int bi = blockIdx.x;
  const int bh = bi >> 2, q = bi & 3;
  const int b = bh >> 3, hh = bh & 7;

  const float orig_s = sArr[bh * N_ + tid];
  float sv_r = orig_s;
  float tv_r = tArr[bh * N_ + tid];
  int   ti_r = tid;

  // bitonic sort ascending; strides<64 via shfl, >=64 via LDS
  for (int size = 2; size <= 1024; size <<= 1) {
    for (int stride = size >> 1; stride > 0; stride >>= 1) {
      const bool up = ((tid & size) == 0);
      const bool lower = ((tid & stride) == 0);
      float psv, ptv; int pti;
      if (stride >= 64) {
        sL[tid] = sv_r; tvL[tid] = tv_r; tiL[tid] = ti_r;
        __syncthreads();
        const int p = tid ^ stride;
        psv = sL[p]; ptv = tvL[p]; pti = tiL[p];
        __syncthreads();
      } else {
        psv = __shfl_xor(sv_r, stride);
        ptv = __shfl_xor(tv_r, stride);
        pti = __shfl_xor(ti_r, stride);
      }
      const bool sameDir = (up == lower);
      const bool pLessS = (psv < sv_r);
      if (pLessS == sameDir) sv_r = psv;
      const bool pLessT = (ptv < tv_r) || (ptv == tv_r && pti < ti_r);
      if (pLessT == sameDir) { tv_r = ptv; ti_r = pti; }
    }
  }
  // thread tid holds rank tid; wave w holds ranks 64w..64w+63
  sL[tid] = sv_r; tvL[tid] = tv_r; tiL[tid] = ti_r;

  // inclusive scans of exp(s), exp(0.01 s) in sorted order
  float c1 = __expf(sv_r), c001 = __expf(0.01f * sv_r);
  {
    float a1 = c1, a2 = c001;
#pragma unroll
    for (int off = 1; off < 64; off <<= 1) {
      const float x1 = __shfl_up(a1, off);
      const float x2 = __shfl_up(a2, off);
      if (lane >= off) { a1 += x1; a2 += x2; }
    }
    if (lane == 63) { ws1[wv] = a1; ws2[wv] = a2; }
    __syncthreads();
    float o1 = 0.f, o2 = 0.f;
    for (int ww = 0; ww < 16; ++ww) {
      if (ww < wv) { o1 += ws1[ww]; o2 += ws2[ww]; }
    }
    c1 = a1 + o1; c001 = a2 + o2;
  }
  cum1L[tid] = c1; cum001L[tid] = c001;
  __syncthreads();
  const float totalHi = cum1L[1023];

  // Z, u, v per sorted-t rank (registers + LDS copies for tails)
  float u_r, v_r;
  {
    const float tj = tv_r;
    const float th = -tj;
    int lo = 0, hi = 1024;
    while (lo < hi) { const int mid = (lo + hi) >> 1; if (sL[mid] <= th) lo = mid + 1; else hi = mid; }
    const float S_lo = (lo > 0) ? cum001L[lo - 1] : 0.f;
    const float S_hi = totalHi - ((lo > 0) ? cum1L[lo - 1] : 0.f);
    const float et = __expf(tj), et001 = __expf(0.01f * tj);
    const float Z = et * S_hi + et001 * S_lo;
    u_r = et / Z; v_r = et001 / Z;
    uL[tid] = u_r; vL[tid] = v_r;
  }
  // query rank + exp factors for row i=tid
  {
    const float th = -orig_s;
    int lo = 0, hi = 1024;
    while (lo < hi) { const int mid = (lo + hi) >> 1; if (tvL[mid] <= th) lo = mid + 1; else hi = mid; }
    rkL[tid] = lo;
    esL[tid] = __expf(orig_s);
    es001L[tid] = __expf(0.01f * orig_s);
  }
  __syncthreads();   // all reads of sL/tvL/cum done; union can be re-used

  // chunk raw sums (chunk=16): wave w owns chunks 4w..4w+3 -> csOff[1+c]
  const int whb = bh * (N_ * D_);
  {
    float r1 = 0.f, r2 = 0.f;
#pragma unroll 8
    for (int k2 = 0; k2 < 64; ++k2) {
      const int   j  = __builtin_amdgcn_readlane(ti_r, k2);
      const float uu = bcast_lane(u_r, k2);
      const float vv = bcast_lane(v_r, k2);
      const float w  = Wh[whb + j * 64 + lane];
      r1 += uu * w; r2 += vv * w;
      if ((k2 & 15) == 15) {
        csOff[(4 * wv + (k2 >> 4) + 1) * 64 + lane] = make_float2(r1, r2);
        r1 = 0.f; r2 = 0.f;
      }
    }
  }
  if (tid < 64) csOff[tid] = make_float2(0.f, 0.f);
  __syncthreads();

  // exclusive chunk-offset scan (read to regs, barrier, write back)
  float2 off[4];
  float2 tot = make_float2(0.f, 0.f);
  {
#pragma unroll
    for (int cc = 0; cc < 4; ++cc) {
      const int c = wv * 4 + cc;
      float o1 = 0.f, o2 = 0.f;
      for (int m = 1; m <= c; ++m) {
        const float2 cv = csOff[m * 64 + lane];
        o1 += cv.x; o2 += cv.y;
      }
      off[cc] = make_float2(o1, o2);
      if (c == 63) {
        const float2 last = csOff[64 * 64 + lane];
        tot = make_float2(o1 + last.x, o2 + last.y);
      }
    }
  }
  __syncthreads();
#pragma unroll
  for (int cc = 0; cc < 4; ++cc)
    csOff[(wv * 4 + cc) * 64 + lane] = off[cc];
  if (wv == 15) csOff[64 * 64 + lane] = tot;
  __syncthreads();

  // tail-sum queries + hp (registers) for this quarter's 16 rows/wave
  const int rbase = q * 256 + wv * 16;
  const float T1 = csOff[64 * 64 + lane].x;
  float hpv[16];
#pragma unroll 2
  for (int r = 0; r < 16; ++r) {
    const int i = rbase + r;
    const int rk = rkL[i];
    float i1 = 0.f, i2 = 0.f;
    if (rk > 0) {
      const int idx = rk - 1, c = idx >> 4;
      const float2 co = csOff[c * 64 + lane];
      i1 = co.x; i2 = co.y;
      for (int k = c * 16; k <= idx; ++k) {
        const int j = tiL[k];
        const float w = Wh[whb + j * 64 + lane];
        i1 += uL[k] * w;
        i2 += vL[k] * w;
      }
    }
    hpv[r] = esL[i] * (T1 - i1) + es001L[i] * i2;
  }

  // GEMM: this head's k-slice; hp broadcast via readlane; bias from h==0
  float acc[16];
  const float binit = (hh == 0) ? outb[lane] : 0.f;
#pragma unroll
  for (int r = 0; r < 16; ++r) acc[r] = binit;
#pragma unroll 4
  for (int kc = 0; kc < 64; ++kc) {
    const float wvv = outW[(hh * 64 + kc) * 64 + lane];
#pragma unroll
    for (int r = 0; r < 16; ++r) acc[r] += bcast_lane(hpv[r], kc) * wvv;
  }
#pragma unroll
  for (int r = 0; r < 16; ++r)
    atomicAdd(&out[(b * N_ + rbase + r) * 64 + lane], acc[r]);
}

extern "C" void kernel_launch(void* const* d_in, const int* in_sizes, int n_in,
                              void* d_out, int out_size, void* d_ws, size_t ws_size,
                              hipStream_t stream) {
  const float* h    = (const float*)d_in[0];
  // d_in[1] = adj: all-ones, unused by the module
  const float* W    = (const float*)d_in[2];
  const float* a    = (const float*)d_in[3];
  const float* outW = (const float*)d_in[4];
  const float* outb = (const float*)d_in[5];
  float* out = (float*)d_out;

  float* ws   = (float*)d_ws;
  float* Wh   = ws;                                   // BH*N*D
  float* sArr = Wh + (size_t)BH_ * N_ * D_;           // BH*N each
  float* tArr = sArr + BH_ * N_;

  hipMemsetAsync(out, 0, (size_t)B_ * N_ * 64 * sizeof(float), stream);
  hipLaunchKernelGGL(k_wh,   dim3((B_ * N_) / 16), dim3(256), 0, stream,
                     h, W, a, Wh, sArr, tArr);
  hipLaunchKernelGGL(k_rest, dim3(BH_ * 4), dim3(1024), 0, stream,
                     sArr, tArr, Wh, outW, outb, out);
}

// Round 6
// 178.434 us; speedup vs baseline: 1.4054x; 1.1463x over previous
//
#include <hip/hip_runtime.h>

// GraphAttentionLayer, B=8, N=1024, F_IN=64, HEADS=8, D=64.
// exp(leaky_relu(s_i + t_j)) factorizes across the LeakyReLU branch, so the
// softmax reduces to prefix sums over sorted s / sorted t.  O(N log N + N D).
//
// R8: R7 structure with XCD-aware block mapping in k_rest.
//  R7 evidence: FETCH_SIZE 61.6MB ~= 4x Wh (16MB): the 4 quarter-blocks per
//  (b,h) land on 4 different XCDs (dispatch round-robins blockIdx % 8), so
//  each redundant slice-gather misses the private L2 (cross-XCD ~600-900cyc).
//  Fix: bh = bi & 63, q = bi >> 6  ->  all 4 blocks of a bh are congruent
//  mod 8 -> same XCD; 8 slices/XCD = 2MB fits the 4MB L2.  Gathers become
//  local-L2 hits; FETCH should drop ~3x.

#define B_  8
#define N_  1024
#define H_  8
#define D_  64
#define BH_ 64

__device__ __forceinline__ float bcast_lane(float v, int l) {
  return __int_as_float(__builtin_amdgcn_readlane(__float_as_int(v), l));
}

// ---------------- Kernel A: Wh = h@W (row-blocked), s/t = Wh . a ----------
__global__ __launch_bounds__(256) void k_wh(
    const float* __restrict__ h, const float* __restrict__ W,
    const float* __restrict__ a,
    float* __restrict__ Wh, float* __restrict__ sArr, float* __restrict__ tArr) {
  const int tid = threadIdx.x;
  const int lane = tid & 63;
  const int wid = tid >> 6;            // 0..3; acc0 -> head wid, acc1 -> head wid+4
  const int row0 = blockIdx.x * 16;
  const int b = row0 >> 10;

  float hreg[16];
#pragma unroll
  for (int r = 0; r < 16; ++r) hreg[r] = h[(row0 + r) * 64 + lane];
  const float a_s = a[lane];
  const float a_t = a[64 + lane];

  float acc0[16], acc1[16];
#pragma unroll
  for (int r = 0; r < 16; ++r) { acc0[r] = 0.f; acc1[r] = 0.f; }
#pragma unroll 4
  for (int k = 0; k < 64; ++k) {
    const float w0 = W[k * 512 + tid];
    const float w1 = W[k * 512 + tid + 256];
#pragma unroll
    for (int r = 0; r < 16; ++r) {
      const float hv = bcast_lane(hreg[r], k);   // SGPR broadcast, no LDS
      acc0[r] += hv * w0;
      acc1[r] += hv * w1;
    }
  }
  const int hh0 = wid, hh1 = wid + 4;
#pragma unroll
  for (int r = 0; r < 16; ++r) {
    const int n = (row0 + r) & (N_ - 1);
    Wh[((b * H_ + hh0) * N_ + n) * D_ + lane] = acc0[r];
    Wh[((b * H_ + hh1) * N_ + n) * D_ + lane] = acc1[r];
  }
#pragma unroll
  for (int r = 0; r < 16; ++r) {
    const int n = (row0 + r) & (N_ - 1);
    float s0 = acc0[r] * a_s, t0 = acc0[r] * a_t;
    float s1 = acc1[r] * a_s, t1 = acc1[r] * a_t;
#pragma unroll
    for (int m = 32; m > 0; m >>= 1) {
      s0 += __shfl_xor(s0, m); t0 += __shfl_xor(t0, m);
      s1 += __shfl_xor(s1, m); t1 += __shfl_xor(t1, m);
    }
    if (lane == 0) {
      sArr[(b * H_ + hh0) * N_ + n] = s0;
      tArr[(b * H_ + hh0) * N_ + n] = t0;
      sArr[(b * H_ + hh1) * N_ + n] = s1;
      tArr[(b * H_ + hh1) * N_ + n] = t1;
    }
  }
}

// ---- Kernel B: per (bh, quarter): redundant sort + scans + u/v/qrk,
//      chunk sums (16) + scan, tail-sum queries, hp, GEMM, atomic out ----
__global__ __launch_bounds__(1024) void k_rest(
    const float* __restrict__ sArr, const float* __restrict__ tArr,
    const float* __restrict__ Wh,
    const float* __restrict__ outW, const float* __restrict__ outb,
    float* __restrict__ out) {
  // union region: {sL,tvL,cum1L,cum001L} during sort/scan -> csOff after
  __shared__ float2 uni[65 * 64];                 // 33,280 B
  float* sL      = (float*)uni;                   // [1024]
  float* tvL     = sL + 1024;
  float* cum1L   = tvL + 1024;
  float* cum001L = cum1L + 1024;
  float2* csOff  = uni;                           // [65][64] after re-use
  __shared__ int   tiL[1024];
  __shared__ float uL[1024], vL[1024];
  __shared__ int   rkL[1024];
  __shared__ float esL[1024], es001L[1024];
  __shared__ float ws1[16], ws2[16];

  const int tid = threadIdx.x;
  const int lane = tid & 63;
  const int wv = tid >> 6;
  const int bi = blockIdx.x;
  // XCD-aware mapping: the 4 blocks of a bh are congruent mod 8 -> same XCD.
  const int bh = bi & 63, q = bi >> 6;
  const int b = bh >> 3, hh = bh & 7;

  const float orig_s = sArr[bh * N_ + tid];
  float sv_r = orig_s;
  float tv_r = tArr[bh * N_ + tid];
  int   ti_r = tid;

  // bitonic sort ascending; strides<64 via shfl, >=64 via LDS
  for (int size = 2; size <= 1024; size <<= 1) {
    for (int stride = size >> 1; stride > 0; stride >>= 1) {
      const bool up = ((tid & size) == 0);
      const bool lower = ((tid & stride) == 0);
      float psv, ptv; int pti;
      if (stride >= 64) {
        sL[tid] = sv_r; tvL[tid] = tv_r; tiL[tid] = ti_r;
        __syncthreads();
        const int p = tid ^ stride;
        psv = sL[p]; ptv = tvL[p]; pti = tiL[p];
        __syncthreads();
      } else {
        psv = __shfl_xor(sv_r, stride);
        ptv = __shfl_xor(tv_r, stride);
        pti = __shfl_xor(ti_r, stride);
      }
      const bool sameDir = (up == lower);
      const bool pLessS = (psv < sv_r);
      if (pLessS == sameDir) sv_r = psv;
      const bool pLessT = (ptv < tv_r) || (ptv == tv_r && pti < ti_r);
      if (pLessT == sameDir) { tv_r = ptv; ti_r = pti; }
    }
  }
  // thread tid holds rank tid; wave w holds ranks 64w..64w+63
  sL[tid] = sv_r; tvL[tid] = tv_r; tiL[tid] = ti_r;

  // inclusive scans of exp(s), exp(0.01 s) in sorted order
  float c1 = __expf(sv_r), c001 = __expf(0.01f * sv_r);
  {
    float a1 = c1, a2 = c001;
#pragma unroll
    for (int off = 1; off < 64; off <<= 1) {
      const float x1 = __shfl_up(a1, off);
      const float x2 = __shfl_up(a2, off);
      if (lane >= off) { a1 += x1; a2 += x2; }
    }
    if (lane == 63) { ws1[wv] = a1; ws2[wv] = a2; }
    __syncthreads();
    float o1 = 0.f, o2 = 0.f;
    for (int ww = 0; ww < 16; ++ww) {
      if (ww < wv) { o1 += ws1[ww]; o2 += ws2[ww]; }
    }
    c1 = a1 + o1; c001 = a2 + o2;
  }
  cum1L[tid] = c1; cum001L[tid] = c001;
  __syncthreads();
  const float totalHi = cum1L[1023];

  // Z, u, v per sorted-t rank (registers + LDS copies for tails)
  float u_r, v_r;
  {
    const float tj = tv_r;
    const float th = -tj;
    int lo = 0, hi = 1024;
    while (lo < hi) { const int mid = (lo + hi) >> 1; if (sL[mid] <= th) lo = mid + 1; else hi = mid; }
    const float S_lo = (lo > 0) ? cum001L[lo - 1] : 0.f;
    const float S_hi = totalHi - ((lo > 0) ? cum1L[lo - 1] : 0.f);
    const float et = __expf(tj), et001 = __expf(0.01f * tj);
    const float Z = et * S_hi + et001 * S_lo;
    u_r = et / Z; v_r = et001 / Z;
    uL[tid] = u_r; vL[tid] = v_r;
  }
  // query rank + exp factors for row i=tid
  {
    const float th = -orig_s;
    int lo = 0, hi = 1024;
    while (lo < hi) { const int mid = (lo + hi) >> 1; if (tvL[mid] <= th) lo = mid + 1; else hi = mid; }
    rkL[tid] = lo;
    esL[tid] = __expf(orig_s);
    es001L[tid] = __expf(0.01f * orig_s);
  }
  __syncthreads();   // all reads of sL/tvL/cum done; union can be re-used

  // chunk raw sums (chunk=16): wave w owns chunks 4w..4w+3 -> csOff[1+c]
  const int whb = bh * (N_ * D_);
  {
    float r1 = 0.f, r2 = 0.f;
#pragma unroll 8
    for (int k2 = 0; k2 < 64; ++k2) {
      const int   j  = __builtin_amdgcn_readlane(ti_r, k2);
      const float uu = bcast_lane(u_r, k2);
      const float vv = bcast_lane(v_r, k2);
      const float w  = Wh[whb + j * 64 + lane];
      r1 += uu * w; r2 += vv * w;
      if ((k2 & 15) == 15) {
        csOff[(4 * wv + (k2 >> 4) + 1) * 64 + lane] = make_float2(r1, r2);
        r1 = 0.f; r2 = 0.f;
      }
    }
  }
  if (tid < 64) csOff[tid] = make_float2(0.f, 0.f);
  __syncthreads();

  // exclusive chunk-offset scan (read to regs, barrier, write back)
  float2 off[4];
  float2 tot = make_float2(0.f, 0.f);
  {
#pragma unroll
    for (int cc = 0; cc < 4; ++cc) {
      const int c = wv * 4 + cc;
      float o1 = 0.f, o2 = 0.f;
      for (int m = 1; m <= c; ++m) {
        const float2 cv = csOff[m * 64 + lane];
        o1 += cv.x; o2 += cv.y;
      }
      off[cc] = make_float2(o1, o2);
      if (c == 63) {
        const float2 last = csOff[64 * 64 + lane];
        tot = make_float2(o1 + last.x, o2 + last.y);
      }
    }
  }
  __syncthreads();
#pragma unroll
  for (int cc = 0; cc < 4; ++cc)
    csOff[(wv * 4 + cc) * 64 + lane] = off[cc];
  if (wv == 15) csOff[64 * 64 + lane] = tot;
  __syncthreads();

  // tail-sum queries + hp (registers) for this quarter's 16 rows/wave
  const int rbase = q * 256 + wv * 16;
  const float T1 = csOff[64 * 64 + lane].x;
  float hpv[16];
#pragma unroll 2
  for (int r = 0; r < 16; ++r) {
    const int i = rbase + r;
    const int rk = rkL[i];
    float i1 = 0.f, i2 = 0.f;
    if (rk > 0) {
      const int idx = rk - 1, c = idx >> 4;
      const float2 co = csOff[c * 64 + lane];
      i1 = co.x; i2 = co.y;
      for (int k = c * 16; k <= idx; ++k) {
        const int j = tiL[k];
        const float w = Wh[whb + j * 64 + lane];
        i1 += uL[k] * w;
        i2 += vL[k] * w;
      }
    }
    hpv[r] = esL[i] * (T1 - i1) + es001L[i] * i2;
  }

  // GEMM: this head's k-slice; hp broadcast via readlane; bias from h==0
  float acc[16];
  const float binit = (hh == 0) ? outb[lane] : 0.f;
#pragma unroll
  for (int r = 0; r < 16; ++r) acc[r] = binit;
#pragma unroll 4
  for (int kc = 0; kc < 64; ++kc) {
    const float wvv = outW[(hh * 64 + kc) * 64 + lane];
#pragma unroll
    for (int r = 0; r < 16; ++r) acc[r] += bcast_lane(hpv[r], kc) * wvv;
  }
#pragma unroll
  for (int r = 0; r < 16; ++r)
    atomicAdd(&out[(b * N_ + rbase + r) * 64 + lane], acc[r]);
}

extern "C" void kernel_launch(void* const* d_in, const int* in_sizes, int n_in,
                              void* d_out, int out_size, void* d_ws, size_t ws_size,
                              hipStream_t stream) {
  const float* h    = (const float*)d_in[0];
  // d_in[1] = adj: all-ones, unused by the module
  const float* W    = (const float*)d_in[2];
  const float* a    = (const float*)d_in[3];
  const float* outW = (const float*)d_in[4];
  const float* outb = (const float*)d_in[5];
  float* out = (float*)d_out;

  float* ws   = (float*)d_ws;
  float* Wh   = ws;                                   // BH*N*D
  float* sArr = Wh + (size_t)BH_ * N_ * D_;           // BH*N each
  float* tArr = sArr + BH_ * N_;

  hipMemsetAsync(out, 0, (size_t)B_ * N_ * 64 * sizeof(float), stream);
  hipLaunchKernelGGL(k_wh,   dim3((B_ * N_) / 16), dim3(256), 0, stream,
                     h, W, a, Wh, sArr, tArr);
  hipLaunchKernelGGL(k_rest, dim3(BH_ * 4), dim3(1024), 0, stream,
                     sArr, tArr, Wh, outW, outb, out);
}

// Round 7
// 172.102 us; speedup vs baseline: 1.4571x; 1.0368x over previous
//
#include <hip/hip_runtime.h>

// GraphAttentionLayer, B=8, N=1024, F_IN=64, HEADS=8, D=64.
// exp(leaky_relu(s_i + t_j)) factorizes across the LeakyReLU branch, so the
// softmax reduces to prefix sums over sorted s / sorted t.  O(N log N + N D).
//
// R9 (on R8's XCD-mapped skeleton; FETCH fix confirmed 61.6->8.6MB):
//  - query tail loop: wave-uniform tiL/uL/vL broadcast ds_reads (48/row) ->
//    lane-distributed prefetch (2 vector ds_reads/row) + v_readlane; fixed-16
//    predicated unrolled gathers (parallel loads, no serial waitcnt chain).
//  - chunk-offset scan: O(c) LDS loop -> register segment sums + wsTL
//    cross-wave offsets (<=15 b64 reads).
//  - memset dispatch deleted: k_wh bias-inits out; k_rest atomics add on top.
//  - esL/es001L recomputed from L2-hot sArr (LDS stays < 64KB).

#define B_  8
#define N_  1024
#define H_  8
#define D_  64
#define BH_ 64

__device__ __forceinline__ float bcast_lane(float v, int l) {
  return __int_as_float(__builtin_amdgcn_readlane(__float_as_int(v), l));
}

// ---------------- Kernel A: Wh = h@W (row-blocked), s/t = Wh . a ----------
__global__ __launch_bounds__(256) void k_wh(
    const float* __restrict__ h, const float* __restrict__ W,
    const float* __restrict__ a, const float* __restrict__ outb,
    float* __restrict__ Wh, float* __restrict__ sArr, float* __restrict__ tArr,
    float* __restrict__ out) {
  const int tid = threadIdx.x;
  const int lane = tid & 63;
  const int wid = tid >> 6;            // 0..3; acc0 -> head wid, acc1 -> head wid+4
  const int row0 = blockIdx.x * 16;
  const int b = row0 >> 10;

  float hreg[16];
#pragma unroll
  for (int r = 0; r < 16; ++r) hreg[r] = h[(row0 + r) * 64 + lane];
  const float a_s = a[lane];
  const float a_t = a[64 + lane];

  // bias-init this block's out rows (replaces the memset dispatch)
  const float bv = outb[tid & 63];
#pragma unroll
  for (int j = 0; j < 4; ++j) out[row0 * 64 + j * 256 + tid] = bv;

  float acc0[16], acc1[16];
#pragma unroll
  for (int r = 0; r < 16; ++r) { acc0[r] = 0.f; acc1[r] = 0.f; }
#pragma unroll 4
  for (int k = 0; k < 64; ++k) {
    const float w0 = W[k * 512 + tid];
    const float w1 = W[k * 512 + tid + 256];
#pragma unroll
    for (int r = 0; r < 16; ++r) {
      const float hv = bcast_lane(hreg[r], k);   // SGPR broadcast, no LDS
      acc0[r] += hv * w0;
      acc1[r] += hv * w1;
    }
  }
  const int hh0 = wid, hh1 = wid + 4;
#pragma unroll
  for (int r = 0; r < 16; ++r) {
    const int n = (row0 + r) & (N_ - 1);
    Wh[((b * H_ + hh0) * N_ + n) * D_ + lane] = acc0[r];
    Wh[((b * H_ + hh1) * N_ + n) * D_ + lane] = acc1[r];
  }
#pragma unroll
  for (int r = 0; r < 16; ++r) {
    const int n = (row0 + r) & (N_ - 1);
    float s0 = acc0[r] * a_s, t0 = acc0[r] * a_t;
    float s1 = acc1[r] * a_s, t1 = acc1[r] * a_t;
#pragma unroll
    for (int m = 32; m > 0; m >>= 1) {
      s0 += __shfl_xor(s0, m); t0 += __shfl_xor(t0, m);
      s1 += __shfl_xor(s1, m); t1 += __shfl_xor(t1, m);
    }
    if (lane == 0) {
      sArr[(b * H_ + hh0) * N_ + n] = s0;
      tArr[(b * H_ + hh0) * N_ + n] = t0;
      sArr[(b * H_ + hh1) * N_ + n] = s1;
      tArr[(b * H_ + hh1) * N_ + n] = t1;
    }
  }
}

// ---- Kernel B: per (bh, quarter): redundant sort + scans + u/v/qrk,
//      chunk sums (16) + reg scan, readlane tail queries, GEMM, atomic out --
__global__ __launch_bounds__(1024) void k_rest(
    const float* __restrict__ sArr, const float* __restrict__ tArr,
    const float* __restrict__ Wh,
    const float* __restrict__ outW,
    float* __restrict__ out) {
  // union region: {sL,tvL,cum1L,cum001L} during sort/scan -> csOff after
  __shared__ float2 uni[65 * 64];                 // 33,280 B
  float* sL      = (float*)uni;                   // [1024]
  float* tvL     = sL + 1024;
  float* cum1L   = tvL + 1024;
  float* cum001L = cum1L + 1024;
  float2* csOff  = uni;                           // [65][64] after re-use
  __shared__ int    tiL[1024];
  __shared__ float2 uvL[1024];
  __shared__ int    rkL[1024];
  __shared__ float2 wsTL[16 * 64];
  __shared__ float  ws1[16], ws2[16];

  const int tid = threadIdx.x;
  const int lane = tid & 63;
  const int wv = tid >> 6;
  const int bi = blockIdx.x;
  // XCD-aware mapping: the 4 blocks of a bh are congruent mod 8 -> same XCD.
  const int bh = bi & 63, q = bi >> 6;
  const int b = bh >> 3, hh = bh & 7;

  const float orig_s = sArr[bh * N_ + tid];
  float sv_r = orig_s;
  float tv_r = tArr[bh * N_ + tid];
  int   ti_r = tid;

  // bitonic sort ascending; strides<64 via shfl, >=64 via LDS
  for (int size = 2; size <= 1024; size <<= 1) {
    for (int stride = size >> 1; stride > 0; stride >>= 1) {
      const bool up = ((tid & size) == 0);
      const bool lower = ((tid & stride) == 0);
      float psv, ptv; int pti;
      if (stride >= 64) {
        sL[tid] = sv_r; tvL[tid] = tv_r; tiL[tid] = ti_r;
        __syncthreads();
        const int p = tid ^ stride;
        psv = sL[p]; ptv = tvL[p]; pti = tiL[p];
        __syncthreads();
      } else {
        psv = __shfl_xor(sv_r, stride);
        ptv = __shfl_xor(tv_r, stride);
        pti = __shfl_xor(ti_r, stride);
      }
      const bool sameDir = (up == lower);
      const bool pLessS = (psv < sv_r);
      if (pLessS == sameDir) sv_r = psv;
      const bool pLessT = (ptv < tv_r) || (ptv == tv_r && pti < ti_r);
      if (pLessT == sameDir) { tv_r = ptv; ti_r = pti; }
    }
  }
  // thread tid holds rank tid; wave w holds ranks 64w..64w+63
  sL[tid] = sv_r; tvL[tid] = tv_r; tiL[tid] = ti_r;

  // inclusive scans of exp(s), exp(0.01 s) in sorted order
  float c1 = __expf(sv_r), c001 = __expf(0.01f * sv_r);
  {
    float a1 = c1, a2 = c001;
#pragma unroll
    for (int off = 1; off < 64; off <<= 1) {
      const float x1 = __shfl_up(a1, off);
      const float x2 = __shfl_up(a2, off);
      if (lane >= off) { a1 += x1; a2 += x2; }
    }
    if (lane == 63) { ws1[wv] = a1; ws2[wv] = a2; }
    __syncthreads();
    float o1 = 0.f, o2 = 0.f;
    for (int ww = 0; ww < 16; ++ww) {
      if (ww < wv) { o1 += ws1[ww]; o2 += ws2[ww]; }
    }
    c1 = a1 + o1; c001 = a2 + o2;
  }
  cum1L[tid] = c1; cum001L[tid] = c001;
  __syncthreads();
  const float totalHi = cum1L[1023];

  // Z, u, v per sorted-t rank (registers + uvL for tails)
  float u_r, v_r;
  {
    const float tj = tv_r;
    const float th = -tj;
    int lo = 0, hi = 1024;
    while (lo < hi) { const int mid = (lo + hi) >> 1; if (sL[mid] <= th) lo = mid + 1; else hi = mid; }
    const float S_lo = (lo > 0) ? cum001L[lo - 1] : 0.f;
    const float S_hi = totalHi - ((lo > 0) ? cum1L[lo - 1] : 0.f);
    const float et = __expf(tj), et001 = __expf(0.01f * tj);
    const float Z = et * S_hi + et001 * S_lo;
    u_r = et / Z; v_r = et001 / Z;
    uvL[tid] = make_float2(u_r, v_r);
  }
  // query rank for row i=tid
  {
    const float th = -orig_s;
    int lo = 0, hi = 1024;
    while (lo < hi) { const int mid = (lo + hi) >> 1; if (tvL[mid] <= th) lo = mid + 1; else hi = mid; }
    rkL[tid] = lo;
  }

  // chunk raw sums (chunk=16): wave w owns chunks 4w..4w+3, segments in regs
  const int whb = bh * (N_ * D_);
  float s1[4] = {0.f, 0.f, 0.f, 0.f}, s2[4] = {0.f, 0.f, 0.f, 0.f};
#pragma unroll
  for (int k2 = 0; k2 < 64; ++k2) {
    const int   j  = __builtin_amdgcn_readlane(ti_r, k2);
    const float uu = bcast_lane(u_r, k2);
    const float vv = bcast_lane(v_r, k2);
    const float w  = Wh[whb + j * 64 + lane];
    s1[k2 >> 4] += uu * w;
    s2[k2 >> 4] += vv * w;
  }
  // per-wave totals -> wsTL; barrier also retires all union reads (searches)
  wsTL[wv * 64 + lane] = make_float2(s1[0] + s1[1] + s1[2] + s1[3],
                                     s2[0] + s2[1] + s2[2] + s2[3]);
  __syncthreads();
  float o1 = 0.f, o2 = 0.f;
  for (int ww = 0; ww < 16; ++ww) {
    if (ww < wv) { const float2 t = wsTL[ww * 64 + lane]; o1 += t.x; o2 += t.y; }
  }
  // exclusive chunk offsets into csOff (union region)
  {
    float p1 = o1, p2 = o2;
#pragma unroll
    for (int cc = 0; cc < 4; ++cc) {
      csOff[(4 * wv + cc) * 64 + lane] = make_float2(p1, p2);
      p1 += s1[cc]; p2 += s2[cc];
    }
    if (wv == 15) csOff[64 * 64 + lane] = make_float2(p1, p2);
  }
  __syncthreads();

  // tail-sum queries + hp (registers) for this quarter's 16 rows/wave
  const int rbase = q * 256 + wv * 16;
  const int rl = lane & 15;
  const int   rk_p  = rkL[rbase + rl];
  const float sq    = sArr[bh * N_ + rbase + rl];   // L2-hot reload
  const float es_p  = __expf(sq);
  const float e01_p = __expf(0.01f * sq);
  const float T1 = csOff[64 * 64 + lane].x;
  float hpv[16];
#pragma unroll
  for (int r = 0; r < 16; ++r) {
    const int rk = __builtin_amdgcn_readlane(rk_p, r);
    float i1 = 0.f, i2 = 0.f;
    if (rk > 0) {
      const int idx = rk - 1, c = idx >> 4;
      const float2 co = csOff[c * 64 + lane];
      i1 = co.x; i2 = co.y;
      const int kb = c * 16;
      const int    ti_p = tiL[kb + rl];      // lane-distributed slice
      const float2 uv_p = uvL[kb + rl];
      const int tail = idx & 15;
#pragma unroll
      for (int kk = 0; kk < 16; ++kk) {
        const int j = __builtin_amdgcn_readlane(ti_p, kk);
        float uu = bcast_lane(uv_p.x, kk);
        float vv = bcast_lane(uv_p.y, kk);
        uu = (kk <= tail) ? uu : 0.f;
        vv = (kk <= tail) ? vv : 0.f;
        const float w = Wh[whb + j * 64 + lane];
        i1 += uu * w;
        i2 += vv * w;
      }
    }
    hpv[r] = bcast_lane(es_p, r) * (T1 - i1) + bcast_lane(e01_p, r) * i2;
  }

  // GEMM: this head's k-slice; hp broadcast via readlane; bias pre-applied
  float acc[16];
#pragma unroll
  for (int r = 0; r < 16; ++r) acc[r] = 0.f;
#pragma unroll 4
  for (int kc = 0; kc < 64; ++kc) {
    const float wvv = outW[(hh * 64 + kc) * 64 + lane];
#pragma unroll
    for (int r = 0; r < 16; ++r) acc[r] += bcast_lane(hpv[r], kc) * wvv;
  }
#pragma unroll
  for (int r = 0; r < 16; ++r)
    atomicAdd(&out[(b * N_ + rbase + r) * 64 + lane], acc[r]);
}

extern "C" void kernel_launch(void* const* d_in, const int* in_sizes, int n_in,
                              void* d_out, int out_size, void* d_ws, size_t ws_size,
                              hipStream_t stream) {
  const float* h    = (const float*)d_in[0];
  // d_in[1] = adj: all-ones, unused by the module
  const float* W    = (const float*)d_in[2];
  const float* a    = (const float*)d_in[3];
  const float* outW = (const float*)d_in[4];
  const float* outb = (const float*)d_in[5];
  float* out = (float*)d_out;

  float* ws   = (float*)d_ws;
  float* Wh   = ws;                                   // BH*N*D
  float* sArr = Wh + (size_t)BH_ * N_ * D_;           // BH*N each
  float* tArr = sArr + BH_ * N_;

  hipLaunchKernelGGL(k_wh,   dim3((B_ * N_) / 16), dim3(256), 0, stream,
                     h, W, a, outb, Wh, sArr, tArr, out);
  hipLaunchKernelGGL(k_rest, dim3(BH_ * 4), dim3(1024), 0, stream,
                     sArr, tArr, Wh, outW, out);
}

// Round 8
// 158.841 us; speedup vs baseline: 1.5787x; 1.0835x over previous
//
#include <hip/hip_runtime.h>

// GraphAttentionLayer, B=8, N=1024, F_IN=64, HEADS=8, D=64.
// exp(leaky_relu(s_i + t_j)) factorizes across the LeakyReLU branch, so the
// softmax reduces to prefix sums over sorted s / sorted t.  O(N log N + N D).
//
// R10: back to the champion R4 4-kernel skeleton (155us; INC materialization
// makes queries O(1) instead of O(16) gathers -- R9 proved the gathers are
// the expensive primitive).  Applied only proven mechanisms:
//  - k_inc XCD remap (R8: -7x FETCH on identical pattern): all 32 chunk
//    blocks of a bh land on XCD bh&7, same XCD k_sort warmed with that slice.
//  - k_sort chunk sums from own-wave sort registers via readlane (R5-proven);
//    cross-wave offsets via wsT table; csL staging deleted.
//  - INC1/INC2 -> interleaved float2 INC12: k_out does 1x512B gather per
//    row-head instead of 2x256B; T1 comes from the cOff grand total.

#define B_  8
#define N_  1024
#define H_  8
#define D_  64
#define BH_ 64
#define CH_ 32          // chunks per (b,h)
#define CL_ 32          // ranks per chunk

__device__ __forceinline__ float bcast_lane(float v, int l) {
  return __int_as_float(__builtin_amdgcn_readlane(__float_as_int(v), l));
}

// ---------------- Kernel A: Wh = h@W (row-blocked), s/t = Wh . a ----------
__global__ __launch_bounds__(256) void k_wh(
    const float* __restrict__ h, const float* __restrict__ W,
    const float* __restrict__ a,
    float* __restrict__ Wh, float* __restrict__ sArr, float* __restrict__ tArr) {
  const int tid = threadIdx.x;
  const int lane = tid & 63;
  const int wid = tid >> 6;            // 0..3; acc0 -> head wid, acc1 -> head wid+4
  const int row0 = blockIdx.x * 16;
  const int b = row0 >> 10;

  float hreg[16];
#pragma unroll
  for (int r = 0; r < 16; ++r) hreg[r] = h[(row0 + r) * 64 + lane];
  const float a_s = a[lane];
  const float a_t = a[64 + lane];

  float acc0[16], acc1[16];
#pragma unroll
  for (int r = 0; r < 16; ++r) { acc0[r] = 0.f; acc1[r] = 0.f; }
#pragma unroll 4
  for (int k = 0; k < 64; ++k) {
    const float w0 = W[k * 512 + tid];
    const float w1 = W[k * 512 + tid + 256];
#pragma unroll
    for (int r = 0; r < 16; ++r) {
      const float hv = bcast_lane(hreg[r], k);   // SGPR broadcast, no LDS
      acc0[r] += hv * w0;
      acc1[r] += hv * w1;
    }
  }
  const int hh0 = wid, hh1 = wid + 4;
#pragma unroll
  for (int r = 0; r < 16; ++r) {
    const int n = (row0 + r) & (N_ - 1);
    Wh[((b * H_ + hh0) * N_ + n) * D_ + lane] = acc0[r];
    Wh[((b * H_ + hh1) * N_ + n) * D_ + lane] = acc1[r];
  }
#pragma unroll
  for (int r = 0; r < 16; ++r) {
    const int n = (row0 + r) & (N_ - 1);
    float s0 = acc0[r] * a_s, t0 = acc0[r] * a_t;
    float s1 = acc1[r] * a_s, t1 = acc1[r] * a_t;
#pragma unroll
    for (int m = 32; m > 0; m >>= 1) {
      s0 += __shfl_xor(s0, m); t0 += __shfl_xor(t0, m);
      s1 += __shfl_xor(s1, m); t1 += __shfl_xor(t1, m);
    }
    if (lane == 0) {
      sArr[(b * H_ + hh0) * N_ + n] = s0;
      tArr[(b * H_ + hh0) * N_ + n] = t0;
      sArr[(b * H_ + hh1) * N_ + n] = s1;
      tArr[(b * H_ + hh1) * N_ + n] = t1;
    }
  }
}

// ---- Kernel B: per (b,h): dual shfl-bitonic sort, shfl scans, Z/u/v,
//      query ranks, chunk sums from OWN registers + cOff (float2) ----
__global__ __launch_bounds__(1024) void k_sort(
    const float* __restrict__ sArr, const float* __restrict__ tArr,
    const float* __restrict__ Wh,
    int* __restrict__ tsi, float2* __restrict__ uvArr,
    int* __restrict__ qrk, float2* __restrict__ cOff) {
  __shared__ float sL[1024];
  __shared__ float tvL[1024];
  __shared__ int   tiL[1024];
  __shared__ float cum1L[1024], cum001L[1024];
  __shared__ float2 wsT[16 * 64];
  __shared__ float ws1[16], ws2[16];
  const int tid = threadIdx.x;
  const int lane = tid & 63;
  const int wv_ = tid >> 6;
  const int bh = blockIdx.x;

  const float orig_s = sArr[bh * N_ + tid];
  float sv_r = orig_s;
  float tv_r = tArr[bh * N_ + tid];
  int   ti_r = tid;

  // bitonic sort ascending; strides<64 via shfl (no barrier), >=64 via LDS
  for (int size = 2; size <= 1024; size <<= 1) {
    for (int stride = size >> 1; stride > 0; stride >>= 1) {
      const bool up = ((tid & size) == 0);
      const bool lower = ((tid & stride) == 0);
      float psv, ptv; int pti;
      if (stride >= 64) {
        sL[tid] = sv_r; tvL[tid] = tv_r; tiL[tid] = ti_r;
        __syncthreads();
        const int p = tid ^ stride;
        psv = sL[p]; ptv = tvL[p]; pti = tiL[p];
        __syncthreads();
      } else {
        psv = __shfl_xor(sv_r, stride);
        ptv = __shfl_xor(tv_r, stride);
        pti = __shfl_xor(ti_r, stride);
      }
      const bool sameDir = (up == lower);
      // s: value-only (ties harmless)
      const bool pLessS = (psv < sv_r);
      if (pLessS == sameDir) sv_r = psv;
      // t: lexicographic (value, idx) for a strict total order
      const bool pLessT = (ptv < tv_r) || (ptv == tv_r && pti < ti_r);
      if (pLessT == sameDir) { tv_r = ptv; ti_r = pti; }
    }
  }
  // thread tid holds rank tid; wave w holds ranks 64w..64w+63
  sL[tid] = sv_r; tvL[tid] = tv_r;

  // inclusive scans of exp(s), exp(0.01 s) in sorted order
  float c1 = __expf(sv_r), c001 = __expf(0.01f * sv_r);
  {
    float a1 = c1, a2 = c001;
#pragma unroll
    for (int off = 1; off < 64; off <<= 1) {
      const float x1 = __shfl_up(a1, off);
      const float x2 = __shfl_up(a2, off);
      if (lane >= off) { a1 += x1; a2 += x2; }
    }
    if (lane == 63) { ws1[wv_] = a1; ws2[wv_] = a2; }
    __syncthreads();
    float o1 = 0.f, o2 = 0.f;
    for (int ww = 0; ww < 16; ++ww) {
      if (ww < wv_) { o1 += ws1[ww]; o2 += ws2[ww]; }
    }
    c1 = a1 + o1; c001 = a2 + o2;
  }
  cum1L[tid] = c1; cum001L[tid] = c001;
  __syncthreads();
  const float totalHi = cum1L[1023];

  // per sorted-t rank: Z, u = e^t/Z, v = e^{0.01t}/Z (registers + global)
  float u_r, v_r;
  {
    const float tj = tv_r;
    const float th = -tj;
    int lo = 0, hi = 1024;   // count of sorted-s <= th
    while (lo < hi) { const int mid = (lo + hi) >> 1; if (sL[mid] <= th) lo = mid + 1; else hi = mid; }
    const float S_lo = (lo > 0) ? cum001L[lo - 1] : 0.f;
    const float S_hi = totalHi - ((lo > 0) ? cum1L[lo - 1] : 0.f);
    const float et = __expf(tj), et001 = __expf(0.01f * tj);
    const float Z = et * S_hi + et001 * S_lo;
    u_r = et / Z; v_r = et001 / Z;
    uvArr[bh * N_ + tid] = make_float2(u_r, v_r);
    tsi[bh * N_ + tid] = ti_r;
  }
  // query rank for row i=tid: count of t_j <= -s_i (value-only, ties ok)
  {
    const float th = -orig_s;
    int lo = 0, hi = 1024;
    while (lo < hi) { const int mid = (lo + hi) >> 1; if (tvL[mid] <= th) lo = mid + 1; else hi = mid; }
    qrk[bh * N_ + tid] = lo;
  }

  // chunk sums (CH_=32 chunks of CL_=32) from OWN-wave sort registers:
  // wave w holds ranks 64w..64w+63 = chunks 2w (lanes 0-31), 2w+1 (32-63).
  const int whb = bh * (N_ * D_);
  float r1a = 0.f, r2a = 0.f, r1b = 0.f, r2b = 0.f;
#pragma unroll 8
  for (int k2 = 0; k2 < CL_; ++k2) {
    const int   ja = __builtin_amdgcn_readlane(ti_r, k2);
    const float ua = bcast_lane(u_r, k2);
    const float va = bcast_lane(v_r, k2);
    const int   jb = __builtin_amdgcn_readlane(ti_r, 32 + k2);
    const float ub = bcast_lane(u_r, 32 + k2);
    const float vb = bcast_lane(v_r, 32 + k2);
    const float wa = Wh[whb + ja * 64 + lane];
    const float wb = Wh[whb + jb * 64 + lane];
    r1a += ua * wa; r2a += va * wa;
    r1b += ub * wb; r2b += vb * wb;
  }
  wsT[wv_ * 64 + lane] = make_float2(r1a + r1b, r2a + r2b);
  __syncthreads();
  float o1 = 0.f, o2 = 0.f;
  for (int ww = 0; ww < 16; ++ww) {
    if (ww < wv_) { const float2 t = wsT[ww * 64 + lane]; o1 += t.x; o2 += t.y; }
  }
  const int cb = bh * 33;
  cOff[(cb + 2 * wv_) * 64 + lane]     = make_float2(o1, o2);
  cOff[(cb + 2 * wv_ + 1) * 64 + lane] = make_float2(o1 + r1a, o2 + r2a);
  if (wv_ == 15)
    cOff[(cb + 32) * 64 + lane] = make_float2(o1 + r1a + r1b, o2 + r2a + r2b);
}

// ---- Kernel C: inclusive per-rank prefix vectors INC12, XCD-remapped -----
__global__ __launch_bounds__(64) void k_inc(
    const float* __restrict__ Wh, const int* __restrict__ tsi,
    const float2* __restrict__ uvArr, const float2* __restrict__ cOff,
    float2* __restrict__ INC12) {
  // remap: all 32 chunk-blocks of a bh are congruent mod 8 -> same XCD as
  // k_sort's block bh (which warmed L2 with this Wh slice).
  const int blk = blockIdx.x;
  const int bh = ((blk >> 8) << 3) | (blk & 7);
  const int c  = (blk >> 3) & 31;
  const int d = threadIdx.x;
  const float2 off = cOff[(bh * 33 + c) * 64 + d];
  float r1 = off.x, r2 = off.y;
  const int base = bh * N_ + c * CL_;
  const int whb = bh * (N_ * D_);
#pragma unroll 8
  for (int k2 = 0; k2 < CL_; ++k2) {
    const int j = tsi[base + k2];
    const float2 uv = uvArr[base + k2];
    const float w = Wh[whb + j * 64 + d];
    r1 += uv.x * w;
    r2 += uv.y * w;
    INC12[(base + k2) * 64 + d] = make_float2(r1, r2);
  }
}

// ---- Kernel D: hp in registers (wave p == head p), GEMM via readlane ----
__global__ __launch_bounds__(512) void k_out(
    const float* __restrict__ sArr, const int* __restrict__ qrk,
    const float2* __restrict__ INC12, const float2* __restrict__ cOff,
    const float* __restrict__ outW, const float* __restrict__ outb,
    float* __restrict__ out) {
  __shared__ float part[8 * 8 * 64];
  __shared__ int   rkI[16 * 8];
  __shared__ float esL[16 * 8], es001L[16 * 8];
  const int tid = threadIdx.x;
  const int row0 = blockIdx.x * 16;
  const int b = row0 >> 10;
  const int p = tid >> 6;        // wave id == head hh == k-slice owner
  const int lane = tid & 63;     // d in phase 1, output col in phase 2/3

  if (tid < 128) {
    const int r = tid >> 3, hh = tid & 7;
    const int bh = b * H_ + hh;
    const int n = (row0 + r) & (N_ - 1);
    const float si = sArr[bh * N_ + n];
    rkI[tid] = qrk[bh * N_ + n];
    esL[tid] = __expf(si);
    es001L[tid] = __expf(0.01f * si);
  }
  __syncthreads();

  // phase 1: hpv[r] = hp[row0+r][p*64+lane] entirely in registers
  float hpv[16];
  {
    const int bh = b * H_ + p;
    const float T1 = cOff[(bh * 33 + 32) * 64 + lane].x;
#pragma unroll
    for (int r = 0; r < 16; ++r) {
      const int rk = rkI[r * 8 + p];
      float i1 = 0.f, i2 = 0.f;
      if (rk > 0) {
        const float2 I = INC12[(bh * N_ + rk - 1) * 64 + lane];
        i1 = I.x; i2 = I.y;
      }
      hpv[r] = esL[r * 8 + p] * (T1 - i1) + es001L[r * 8 + p] * i2;
    }
  }

  // phase 2: wave p owns k in [p*64, p*64+64); hp broadcast via readlane
  float acc[16];
#pragma unroll
  for (int r = 0; r < 16; ++r) acc[r] = 0.f;
#pragma unroll 4
  for (int kc = 0; kc < 64; ++kc) {
    const float wvv = outW[(p * 64 + kc) * 64 + lane];
#pragma unroll
    for (int r = 0; r < 16; ++r) {
      const float hv = bcast_lane(hpv[r], kc);   // SGPR broadcast, no LDS
      acc[r] += hv * wvv;
    }
  }

  // phase 3: reduce the 8 per-wave partials
  for (int half = 0; half < 2; ++half) {
#pragma unroll
    for (int r = 0; r < 8; ++r) part[(p * 8 + r) * 64 + lane] = acc[half * 8 + r];
    __syncthreads();
    {
      const int r2 = tid >> 6, c2 = tid & 63;
      float ssum = 0.f;
#pragma unroll
      for (int p2 = 0; p2 < 8; ++p2) ssum += part[(p2 * 8 + r2) * 64 + c2];
      out[(row0 + half * 8 + r2) * 64 + c2] = outb[c2] + ssum;
    }
    __syncthreads();
  }
}

extern "C" void kernel_launch(void* const* d_in, const int* in_sizes, int n_in,
                              void* d_out, int out_size, void* d_ws, size_t ws_size,
                              hipStream_t stream) {
  const float* h    = (const float*)d_in[0];
  // d_in[1] = adj: all-ones, unused by the module
  const float* W    = (const float*)d_in[2];
  const float* a    = (const float*)d_in[3];
  const float* outW = (const float*)d_in[4];
  const float* outb = (const float*)d_in[5];
  float* out = (float*)d_out;

  float* ws   = (float*)d_ws;
  float* Wh   = ws;                                   // BH*N*D
  float* sArr = Wh + (size_t)BH_ * N_ * D_;           // BH*N each
  float* tArr = sArr + BH_ * N_;
  int*   tsi  = (int*)(tArr + BH_ * N_);
  int*   qrk  = tsi + BH_ * N_;
  float2* uvArr = (float2*)(qrk + BH_ * N_);          // BH*N float2
  float2* cOff  = uvArr + (size_t)BH_ * N_;           // BH*33*64 float2
  float2* INC12 = cOff + (size_t)BH_ * 33 * 64;       // BH*N*64 float2

  hipLaunchKernelGGL(k_wh,   dim3((B_ * N_) / 16), dim3(256), 0, stream,
                     h, W, a, Wh, sArr, tArr);
  hipLaunchKernelGGL(k_sort, dim3(BH_), dim3(1024), 0, stream,
                     sArr, tArr, Wh, tsi, uvArr, qrk, cOff);
  hipLaunchKernelGGL(k_inc,  dim3(BH_ * CH_), dim3(64), 0, stream,
                     Wh, tsi, uvArr, cOff, INC12);
  hipLaunchKernelGGL(k_out,  dim3((B_ * N_) / 16), dim3(512), 0, stream,
                     sArr, qrk, INC12, cOff, outW, outb, out);
}

// Round 9
// 156.001 us; speedup vs baseline: 1.6074x; 1.0182x over previous
//
#include <hip/hip_runtime.h>

// GraphAttentionLayer, B=8, N=1024, F_IN=64, HEADS=8, D=64.
// exp(leaky_relu(s_i + t_j)) factorizes across the LeakyReLU branch, so the
// softmax reduces to prefix sums over sorted s / sorted t.  O(N log N + N D).
//
// R11: 3 launches.  Session model: dur = fill(44) + 11.5/launch + content.
// k_inc merged into k_sort WITHOUT the prior failure modes:
//  - R5 failed: INC at 64 blocks (1/4 chip).  Here: 256 blocks (4/bh), each
//    block redundantly sorts (wall-free, distinct CUs) and emits its QUARTER
//    of INC12 at full chip width (waves 0-7, one chunk each).
//  - R8/R9 failed: dropped INC materialization -> O(16) query gathers.
//    Here INC12 stays materialized; k_out queries remain O(1).
//  - XCD alignment: bi = q*64+bh -> all 4 quarters of bh on XCD bh&7; the
//    INC Wh gathers hit the same block's chunk-sum-phase L1/L2 lines.
//  - u/v/ti republished into dead cum1L/cum001L/tiL LDS (zero extra LDS);
//    tsi/uvArr globals deleted; qrk searches quarter-guarded (wave-uniform).

#define B_  8
#define N_  1024
#define H_  8
#define D_  64
#define BH_ 64
#define CH_ 32          // chunks per (b,h)
#define CL_ 32          // ranks per chunk

__device__ __forceinline__ float bcast_lane(float v, int l) {
  return __int_as_float(__builtin_amdgcn_readlane(__float_as_int(v), l));
}

// ---------------- Kernel A: Wh = h@W (row-blocked), s/t = Wh . a ----------
__global__ __launch_bounds__(256) void k_wh(
    const float* __restrict__ h, const float* __restrict__ W,
    const float* __restrict__ a,
    float* __restrict__ Wh, float* __restrict__ sArr, float* __restrict__ tArr) {
  const int tid = threadIdx.x;
  const int lane = tid & 63;
  const int wid = tid >> 6;            // 0..3; acc0 -> head wid, acc1 -> head wid+4
  const int row0 = blockIdx.x * 16;
  const int b = row0 >> 10;

  float hreg[16];
#pragma unroll
  for (int r = 0; r < 16; ++r) hreg[r] = h[(row0 + r) * 64 + lane];
  const float a_s = a[lane];
  const float a_t = a[64 + lane];

  float acc0[16], acc1[16];
#pragma unroll
  for (int r = 0; r < 16; ++r) { acc0[r] = 0.f; acc1[r] = 0.f; }
#pragma unroll 4
  for (int k = 0; k < 64; ++k) {
    const float w0 = W[k * 512 + tid];
    const float w1 = W[k * 512 + tid + 256];
#pragma unroll
    for (int r = 0; r < 16; ++r) {
      const float hv = bcast_lane(hreg[r], k);   // SGPR broadcast, no LDS
      acc0[r] += hv * w0;
      acc1[r] += hv * w1;
    }
  }
  const int hh0 = wid, hh1 = wid + 4;
#pragma unroll
  for (int r = 0; r < 16; ++r) {
    const int n = (row0 + r) & (N_ - 1);
    Wh[((b * H_ + hh0) * N_ + n) * D_ + lane] = acc0[r];
    Wh[((b * H_ + hh1) * N_ + n) * D_ + lane] = acc1[r];
  }
#pragma unroll
  for (int r = 0; r < 16; ++r) {
    const int n = (row0 + r) & (N_ - 1);
    float s0 = acc0[r] * a_s, t0 = acc0[r] * a_t;
    float s1 = acc1[r] * a_s, t1 = acc1[r] * a_t;
#pragma unroll
    for (int m = 32; m > 0; m >>= 1) {
      s0 += __shfl_xor(s0, m); t0 += __shfl_xor(t0, m);
      s1 += __shfl_xor(s1, m); t1 += __shfl_xor(t1, m);
    }
    if (lane == 0) {
      sArr[(b * H_ + hh0) * N_ + n] = s0;
      tArr[(b * H_ + hh0) * N_ + n] = t0;
      sArr[(b * H_ + hh1) * N_ + n] = s1;
      tArr[(b * H_ + hh1) * N_ + n] = t1;
    }
  }
}

// ---- Kernel B: per (bh, quarter q): redundant dual sort, scans, Z/u/v,
//      quarter qrk, chunk sums + chOff, quarter of INC12 (waves 0..7) ----
__global__ __launch_bounds__(1024) void k_sortinc(
    const float* __restrict__ sArr, const float* __restrict__ tArr,
    const float* __restrict__ Wh,
    int* __restrict__ qrk, float2* __restrict__ cOff,
    float2* __restrict__ INC12) {
  __shared__ float sL[1024];
  __shared__ float tvL[1024];
  __shared__ int   tiL[1024];
  __shared__ float cum1L[1024], cum001L[1024];   // reused as uL/vL after Z
  __shared__ float2 wsT[16 * 64];
  __shared__ float2 chOff[CH_ * 64];
  __shared__ float ws1[16], ws2[16];
  const int tid = threadIdx.x;
  const int lane = tid & 63;
  const int wv_ = tid >> 6;
  const int bi = blockIdx.x;
  const int bh = bi & 63, q = bi >> 6;   // 4 quarters of bh on XCD bh&7

  const float orig_s = sArr[bh * N_ + tid];
  float sv_r = orig_s;
  float tv_r = tArr[bh * N_ + tid];
  int   ti_r = tid;

  // bitonic sort ascending; strides<64 via shfl (no barrier), >=64 via LDS
  for (int size = 2; size <= 1024; size <<= 1) {
    for (int stride = size >> 1; stride > 0; stride >>= 1) {
      const bool up = ((tid & size) == 0);
      const bool lower = ((tid & stride) == 0);
      float psv, ptv; int pti;
      if (stride >= 64) {
        sL[tid] = sv_r; tvL[tid] = tv_r; tiL[tid] = ti_r;
        __syncthreads();
        const int p = tid ^ stride;
        psv = sL[p]; ptv = tvL[p]; pti = tiL[p];
        __syncthreads();
      } else {
        psv = __shfl_xor(sv_r, stride);
        ptv = __shfl_xor(tv_r, stride);
        pti = __shfl_xor(ti_r, stride);
      }
      const bool sameDir = (up == lower);
      // s: value-only (ties harmless)
      const bool pLessS = (psv < sv_r);
      if (pLessS == sameDir) sv_r = psv;
      // t: lexicographic (value, idx) for a strict total order
      const bool pLessT = (ptv < tv_r) || (ptv == tv_r && pti < ti_r);
      if (pLessT == sameDir) { tv_r = ptv; ti_r = pti; }
    }
  }
  // thread tid holds rank tid; wave w holds ranks 64w..64w+63
  sL[tid] = sv_r; tvL[tid] = tv_r; tiL[tid] = ti_r;

  // inclusive scans of exp(s), exp(0.01 s) in sorted order
  float c1 = __expf(sv_r), c001 = __expf(0.01f * sv_r);
  {
    float a1 = c1, a2 = c001;
#pragma unroll
    for (int off = 1; off < 64; off <<= 1) {
      const float x1 = __shfl_up(a1, off);
      const float x2 = __shfl_up(a2, off);
      if (lane >= off) { a1 += x1; a2 += x2; }
    }
    if (lane == 63) { ws1[wv_] = a1; ws2[wv_] = a2; }
    __syncthreads();
    float o1 = 0.f, o2 = 0.f;
    for (int ww = 0; ww < 16; ++ww) {
      if (ww < wv_) { o1 += ws1[ww]; o2 += ws2[ww]; }
    }
    c1 = a1 + o1; c001 = a2 + o2;
  }
  cum1L[tid] = c1; cum001L[tid] = c001;
  __syncthreads();
  const float totalHi = cum1L[1023];

  // per sorted-t rank: Z, u = e^t/Z, v = e^{0.01t}/Z (registers only)
  float u_r, v_r;
  {
    const float tj = tv_r;
    const float th = -tj;
    int lo = 0, hi = 1024;   // count of sorted-s <= th
    while (lo < hi) { const int mid = (lo + hi) >> 1; if (sL[mid] <= th) lo = mid + 1; else hi = mid; }
    const float S_lo = (lo > 0) ? cum001L[lo - 1] : 0.f;
    const float S_hi = totalHi - ((lo > 0) ? cum1L[lo - 1] : 0.f);
    const float et = __expf(tj), et001 = __expf(0.01f * tj);
    const float Z = et * S_hi + et001 * S_lo;
    u_r = et / Z; v_r = et001 / Z;
  }
  // query rank for own quarter only (wave-uniform guard)
  if ((tid >> 8) == q) {
    const float th = -orig_s;
    int lo = 0, hi = 1024;
    while (lo < hi) { const int mid = (lo + hi) >> 1; if (tvL[mid] <= th) lo = mid + 1; else hi = mid; }
    qrk[bh * N_ + tid] = lo;
  }
  __syncthreads();          // retire all sL/tvL/cum reads
  // republish u/v into dead scan arrays for the INC phase
  cum1L[tid] = u_r; cum001L[tid] = v_r;

  // chunk sums (32 chunks of 32) from OWN-wave sort registers:
  // wave w holds ranks 64w..64w+63 = chunks 2w (lanes 0-31), 2w+1 (32-63).
  const int whb = bh * (N_ * D_);
  float r1a = 0.f, r2a = 0.f, r1b = 0.f, r2b = 0.f;
#pragma unroll 8
  for (int k2 = 0; k2 < CL_; ++k2) {
    const int   ja = __builtin_amdgcn_readlane(ti_r, k2);
    const float ua = bcast_lane(u_r, k2);
    const float va = bcast_lane(v_r, k2);
    const int   jb = __builtin_amdgcn_readlane(ti_r, 32 + k2);
    const float ub = bcast_lane(u_r, 32 + k2);
    const float vb = bcast_lane(v_r, 32 + k2);
    const float wa = Wh[whb + ja * 64 + lane];
    const float wb = Wh[whb + jb * 64 + lane];
    r1a += ua * wa; r2a += va * wa;
    r1b += ub * wb; r2b += vb * wb;
  }
  wsT[wv_ * 64 + lane] = make_float2(r1a + r1b, r2a + r2b);
  __syncthreads();
  float o1 = 0.f, o2 = 0.f;
  for (int ww = 0; ww < 16; ++ww) {
    if (ww < wv_) { const float2 t = wsT[ww * 64 + lane]; o1 += t.x; o2 += t.y; }
  }
  // exclusive chunk offsets: LDS (for own INC quarter) + global (q==0 only)
  chOff[(2 * wv_) * 64 + lane]     = make_float2(o1, o2);
  chOff[(2 * wv_ + 1) * 64 + lane] = make_float2(o1 + r1a, o2 + r2a);
  if (q == 0) {
    const int cb = bh * 33;
    cOff[(cb + 2 * wv_) * 64 + lane]     = make_float2(o1, o2);
    cOff[(cb + 2 * wv_ + 1) * 64 + lane] = make_float2(o1 + r1a, o2 + r2a);
    if (wv_ == 15)
      cOff[(cb + 32) * 64 + lane] = make_float2(o1 + r1a + r1b, o2 + r2a + r2b);
  }
  __syncthreads();          // chOff + republished u/v visible

  // INC quarter: waves 0..7 -> chunks 8q..8q+7 (ranks 256q..256q+255).
  // Wh slice is L1/L2-hot from the chunk-sum phase of this same block.
  if (wv_ < 8) {
    const int cc = q * 8 + wv_;
    const float2 off = chOff[cc * 64 + lane];
    float r1 = off.x, r2 = off.y;
    const int rb = bh * N_ + cc * CL_;
#pragma unroll 8
    for (int k2 = 0; k2 < CL_; ++k2) {
      const int   j  = tiL[cc * CL_ + k2];       // LDS broadcasts (cheap, R4)
      const float uu = cum1L[cc * CL_ + k2];
      const float vv = cum001L[cc * CL_ + k2];
      const float w  = Wh[whb + j * 64 + lane];
      r1 += uu * w;
      r2 += vv * w;
      INC12[(rb + k2) * 64 + lane] = make_float2(r1, r2);
    }
  }
}

// ---- Kernel C: hp in registers (wave p == head p), GEMM via readlane ----
__global__ __launch_bounds__(512) void k_out(
    const float* __restrict__ sArr, const int* __restrict__ qrk,
    const float2* __restrict__ INC12, const float2* __restrict__ cOff,
    const float* __restrict__ outW, const float* __restrict__ outb,
    float* __restrict__ out) {
  __shared__ float part[8 * 8 * 64];
  __shared__ int   rkI[16 * 8];
  __shared__ float esL[16 * 8], es001L[16 * 8];
  const int tid = threadIdx.x;
  const int row0 = blockIdx.x * 16;
  const int b = row0 >> 10;
  const int p = tid >> 6;        // wave id == head hh == k-slice owner
  const int lane = tid & 63;     // d in phase 1, output col in phase 2/3

  if (tid < 128) {
    const int r = tid >> 3, hh = tid & 7;
    const int bh = b * H_ + hh;
    const int n = (row0 + r) & (N_ - 1);
    const float si = sArr[bh * N_ + n];
    rkI[tid] = qrk[bh * N_ + n];
    esL[tid] = __expf(si);
    es001L[tid] = __expf(0.01f * si);
  }
  __syncthreads();

  // phase 1: hpv[r] = hp[row0+r][p*64+lane] entirely in registers
  float hpv[16];
  {
    const int bh = b * H_ + p;
    const float T1 = cOff[(bh * 33 + 32) * 64 + lane].x;
#pragma unroll
    for (int r = 0; r < 16; ++r) {
      const int rk = rkI[r * 8 + p];
      float i1 = 0.f, i2 = 0.f;
      if (rk > 0) {
        const float2 I = INC12[(bh * N_ + rk - 1) * 64 + lane];
        i1 = I.x; i2 = I.y;
      }
      hpv[r] = esL[r * 8 + p] * (T1 - i1) + es001L[r * 8 + p] * i2;
    }
  }

  // phase 2: wave p owns k in [p*64, p*64+64); hp broadcast via readlane
  float acc[16];
#pragma unroll
  for (int r = 0; r < 16; ++r) acc[r] = 0.f;
#pragma unroll 4
  for (int kc = 0; kc < 64; ++kc) {
    const float wvv = outW[(p * 64 + kc) * 64 + lane];
#pragma unroll
    for (int r = 0; r < 16; ++r) {
      const float hv = bcast_lane(hpv[r], kc);   // SGPR broadcast, no LDS
      acc[r] += hv * wvv;
    }
  }

  // phase 3: reduce the 8 per-wave partials
  for (int half = 0; half < 2; ++half) {
#pragma unroll
    for (int r = 0; r < 8; ++r) part[(p * 8 + r) * 64 + lane] = acc[half * 8 + r];
    __syncthreads();
    {
      const int r2 = tid >> 6, c2 = tid & 63;
      float ssum = 0.f;
#pragma unroll
      for (int p2 = 0; p2 < 8; ++p2) ssum += part[(p2 * 8 + r2) * 64 + c2];
      out[(row0 + half * 8 + r2) * 64 + c2] = outb[c2] + ssum;
    }
    __syncthreads();
  }
}

extern "C" void kernel_launch(void* const* d_in, const int* in_sizes, int n_in,
                              void* d_out, int out_size, void* d_ws, size_t ws_size,
                              hipStream_t stream) {
  const float* h    = (const float*)d_in[0];
  // d_in[1] = adj: all-ones, unused by the module
  const float* W    = (const float*)d_in[2];
  const float* a    = (const float*)d_in[3];
  const float* outW = (const float*)d_in[4];
  const float* outb = (const float*)d_in[5];
  float* out = (float*)d_out;

  float* ws   = (float*)d_ws;
  float* Wh   = ws;                                   // BH*N*D
  float* sArr = Wh + (size_t)BH_ * N_ * D_;           // BH*N each
  float* tArr = sArr + BH_ * N_;
  int*   qrk  = (int*)(tArr + BH_ * N_);
  float2* cOff  = (float2*)(qrk + BH_ * N_);          // BH*33*64 float2
  float2* INC12 = cOff + (size_t)BH_ * 33 * 64;       // BH*N*64 float2

  hipLaunchKernelGGL(k_wh,      dim3((B_ * N_) / 16), dim3(256), 0, stream,
                     h, W, a, Wh, sArr, tArr);
  hipLaunchKernelGGL(k_sortinc, dim3(256), dim3(1024), 0, stream,
                     sArr, tArr, Wh, qrk, cOff, INC12);
  hipLaunchKernelGGL(k_out,     dim3((B_ * N_) / 16), dim3(512), 0, stream,
                     sArr, qrk, INC12, cOff, outW, outb, out);
}